// Round 2
// baseline (907.935 us; speedup 1.0000x reference)
//
#include <hip/hip_runtime.h>
#include <stdint.h>

// Problem constants (from reference)
#define NN 500000          // nodes
#define HH 256             // hidden
#define MBLK 64            // nodes per block
#define NBLK ((NN + MBLK - 1) / MBLK)   // 7813
#define CHUNK_U32 8192     // one staged weight chunk: [256 n][32 k] as hi|lo bf16 = 32KB
#define NCHUNK 17          // W1:1 chunk, W2:8, W3:8

typedef short short8 __attribute__((ext_vector_type(8)));
typedef float floatx4 __attribute__((ext_vector_type(4)));

__device__ __forceinline__ unsigned short f2bf(float f) {
  union { float f; uint32_t u; } v; v.f = f;
  uint32_t r = v.u + 0x7fffu + ((v.u >> 16) & 1u);   // RNE
  return (unsigned short)(r >> 16);
}
__device__ __forceinline__ float bf2f(unsigned short h) {
  union { uint32_t u; float f; } v; v.u = ((uint32_t)h) << 16;
  return v.f;
}
__device__ __forceinline__ float tanh_fast(float x) {
  float xc = fminf(fmaxf(x, -9.0f), 9.0f);           // tanh(9) == 1 - 3e-8
  float e = __expf(2.0f * xc);
  return __fdividef(e - 1.0f, e + 1.0f);
}
__device__ __forceinline__ float log_sigmoid_f(float x) {
  return fminf(x, 0.0f) - log1pf(__expf(-fabsf(x)));
}

// ---------------------------------------------------------------------------
// Pre-kernel: pack W1/W2/W3 (fp32 [k][n]) -> ws as 17 chunks of
// [n 0..255][64 u16] where a row is hi[k'=0..31] ++ lo[k'=0..31], with the
// 16B-granule XOR swizzle (g ^ (n&7)) baked in, so the main kernel can stage
// with LINEAR global_load_lds and do conflict-free ds_read_b128 B-fragments.
// (hi granules 0..3 and lo granules 4..7 stay disjoint under ^s: bit2 differs.)
// Runs every launch (d_ws is re-poisoned by the harness).
// ---------------------------------------------------------------------------
__global__ void __launch_bounds__(256)
pack_weights(const float* __restrict__ W1, const float* __restrict__ W2,
             const float* __restrict__ W3, uint16_t* __restrict__ ws16) {
  int t = blockIdx.x * 256 + threadIdx.x;
  if (t >= NCHUNK * CHUNK_U32) return;
  int chunk = t >> 13;          // /8192
  int r = t & 8191;
  int n  = r & 255;             // coalesced source reads
  int kp = r >> 8;              // 0..31
  float w;
  if (chunk == 0)      w = W1[kp * HH + n];
  else if (chunk <= 8) w = W2[((chunk - 1) * 32 + kp) * HH + n];
  else                 w = W3[((chunk - 9) * 32 + kp) * HH + n];
  unsigned short hi = f2bf(w);
  unsigned short lo = f2bf(w - bf2f(hi));
  uint16_t* row = ws16 + (size_t)chunk * 16384 + n * 64;
  row[((((kp >> 3)    ) ^ (n & 7)) << 3) | (kp & 7)] = hi;
  row[(((4 + (kp >> 3)) ^ (n & 7)) << 3) | (kp & 7)] = lo;
}

// async global->LDS, 16B per lane, linear (dest = uniform base + lane*16)
__device__ __forceinline__ void stage_chunk(const uint32_t* __restrict__ src,
                                            uint32_t* dst, int wave, int lane) {
#pragma unroll
  for (int it = 0; it < 4; ++it) {
    int o = (wave * 4 + it) * 256;     // u32 units; 8 waves x 4 iters x 1KB = 32KB
    __builtin_amdgcn_global_load_lds(
        (const __attribute__((address_space(1))) uint32_t*)(src + o + lane * 4),
        (__attribute__((address_space(3))) uint32_t*)(dst + o), 16, 0, 0);
  }
}

// One k-step (k=32) for all (mt,nt): 3-pass hi/lo split MFMA.
// B-frag: n = lane&15 (nr), k = q*8+j  -> hi granule q, lo granule 4+q.
#define KSTEP(AHI, ALO, WB)                                                    \
  {                                                                            \
    const char* wb8 = (const char*)(WB);                                       \
    _Pragma("unroll")                                                          \
    for (int nt = 0; nt < 4; ++nt) {                                           \
      int nr = cb + nt * 16 + c;                                               \
      short8 bhi = *(const short8*)(wb8 + nr * 128 + ((q ^ (nr & 7)) << 4));   \
      short8 blo = *(const short8*)(wb8 + nr * 128 + (((4 + q) ^ (nr & 7)) << 4)); \
      _Pragma("unroll")                                                        \
      for (int mt = 0; mt < 2; ++mt) {                                         \
        acc[mt][nt] = __builtin_amdgcn_mfma_f32_16x16x32_bf16(AHI[mt], bhi, acc[mt][nt], 0, 0, 0); \
        acc[mt][nt] = __builtin_amdgcn_mfma_f32_16x16x32_bf16(ALO[mt], bhi, acc[mt][nt], 0, 0, 0); \
        acc[mt][nt] = __builtin_amdgcn_mfma_f32_16x16x32_bf16(AHI[mt], blo, acc[mt][nt], 0, 0, 0); \
      }                                                                        \
    }                                                                          \
  }

#define ZEROACC()                                                              \
  {                                                                            \
    _Pragma("unroll") for (int mt = 0; mt < 2; ++mt)                           \
        _Pragma("unroll") for (int nt = 0; nt < 4; ++nt)                       \
            acc[mt][nt] = (floatx4){0.f, 0.f, 0.f, 0.f};                       \
  }

// bias + tanh + pack(hi|lo u32) + swizzled store into hbuf (next layer's A).
// C/D layout (m89): col = lane&15 (c), row = q*4+rr.
#define EPILOGUE_PACK(BIAS)                                                    \
  {                                                                            \
    _Pragma("unroll")                                                          \
    for (int nt = 0; nt < 4; ++nt) {                                           \
      float bv = (BIAS)[cb + nt * 16 + c];                                     \
      _Pragma("unroll")                                                        \
      for (int mt = 0; mt < 2; ++mt) {                                         \
        _Pragma("unroll")                                                      \
        for (int rr = 0; rr < 4; ++rr) {                                       \
          float tv = tanh_fast(acc[mt][nt][rr] + bv);                          \
          unsigned short h_ = f2bf(tv);                                        \
          unsigned short l_ = f2bf(tv - bf2f(h_));                             \
          int row = wr * 32 + mt * 16 + q * 4 + rr;                            \
          int k = cb + nt * 16 + c;                                            \
          hbuf[row * 256 + ((((k >> 2) ^ (row & 15)) << 2) | (k & 3))] =       \
              (uint32_t)h_ | ((uint32_t)l_ << 16);                             \
        }                                                                      \
      }                                                                        \
    }                                                                          \
  }

// ---------------------------------------------------------------------------
// Fused 4-layer MLP. Block = 512 thr (8 waves, 2m x 4n), 64 nodes/block.
// Per wave: 32 rows x 64 cols, mfma_f32_16x16x32_bf16, hi/lo 3-pass
// (a = a_hi + a_lo; D = Ahi*Bhi + Alo*Bhi + Ahi*Blo, ~1e-6 rel err).
// LDS: hbuf 64KB (packed h, swizzled) + 2x32KB weight chunk double-buffer.
// 128KB LDS -> 1 block/CU, 2 waves/SIMD.
// ---------------------------------------------------------------------------
__global__ void __launch_bounds__(512, 2)
mlp_fused(const float* __restrict__ ea, const float* __restrict__ b1,
          const float* __restrict__ b2, const float* __restrict__ b3,
          const float* __restrict__ W4, const float* __restrict__ b4p,
          const uint32_t* __restrict__ wsw, float* __restrict__ out) {
  __shared__ uint32_t smem[32768];          // 128 KB
  uint32_t* hbuf = smem;                    // [64][256] packed u32 (swizzled)
  uint32_t* wbuf = smem + 16384;            // [2][8192]

  const int tid = threadIdx.x;
  const int wave = tid >> 6;
  const int lane = tid & 63;
  const int q = lane >> 4;                  // k-group / D-row-group
  const int c = lane & 15;                  // A-row / B-col / D-col lane
  const int wr = wave >> 2;                 // 0..1  (m)
  const int wc = wave & 3;                  // 0..3  (n)
  const int cb = wc * 64;
  const int blk = blockIdx.x;

  floatx4 acc[2][4];

  // ---- prologue: stage chunk0 (W1) async; load+split g fragments ----
  // A-frag layout: m = c, k = q*8 + j.
  stage_chunk(wsw, wbuf, wave, lane);
  short8 g_hi[2], g_lo[2];
#pragma unroll
  for (int mt = 0; mt < 2; ++mt) {
    int row = blk * 64 + wr * 32 + mt * 16 + c;
    if (row >= NN) row = NN - 1;            // clamp (tail rows' outputs unused)
    const float* gp = ea + (size_t)row * 32 + q * 8;
    floatx4 v0 = *(const floatx4*)gp;
    floatx4 v1 = *(const floatx4*)(gp + 4);
    float g8[8] = {v0[0], v0[1], v0[2], v0[3], v1[0], v1[1], v1[2], v1[3]};
#pragma unroll
    for (int j = 0; j < 8; ++j) {
      unsigned short h_ = f2bf(g8[j]);
      g_hi[mt][j] = (short)h_;
      g_lo[mt][j] = (short)f2bf(g8[j] - bf2f(h_));
    }
  }
  __syncthreads();                          // chunk0 drained (vmcnt0) + visible

  // ---- Layer 1 (K=32: one k-step), stage chunk1 (W2 kc0) meanwhile ----
  stage_chunk(wsw + CHUNK_U32, wbuf + CHUNK_U32, wave, lane);
  ZEROACC();
  KSTEP(g_hi, g_lo, wbuf);
  EPILOGUE_PACK(b1);
  __syncthreads();                          // h1 visible, chunk1 drained

  // ---- Layers 2 and 3: chunks 1..8 / 9..16, 2-phase staged pipeline ----
  // Double-buffer safety: chunk+1 goes to buf (chunk+1)&1, whose last reader
  // (iteration kc-1) passed the barrier at the end of that iteration.
#pragma unroll 1
  for (int lay = 0; lay < 2; ++lay) {
    const int ch0 = 1 + lay * 8;
    ZEROACC();
#pragma unroll 1
    for (int kc = 0; kc < 8; ++kc) {
      const int chunk = ch0 + kc;
      const uint32_t* wcur = wbuf + (chunk & 1) * CHUNK_U32;
      if (chunk + 1 < NCHUNK)
        stage_chunk(wsw + (chunk + 1) * CHUNK_U32,
                    wbuf + ((chunk + 1) & 1) * CHUNK_U32, wave, lane);
      // A fragments from packed h: need k = kc*32 + q*8 + {0..7} of row (m=c)
      // -> u32 granules g0 = kc*8+q*2 and g0+1, positions XORed by row&15.
      short8 ahi[2], alo[2];
#pragma unroll
      for (int mt = 0; mt < 2; ++mt) {
        const int row = wr * 32 + mt * 16 + c;
        const uint32_t* hb = hbuf + row * 256;
        const int g0 = kc * 8 + q * 2;
        uint4 p0 = *(const uint4*)(hb + (((g0) ^ (row & 15)) << 2));
        uint4 p1 = *(const uint4*)(hb + (((g0 + 1) ^ (row & 15)) << 2));
        uint32_t u[8] = {p0.x, p0.y, p0.z, p0.w, p1.x, p1.y, p1.z, p1.w};
#pragma unroll
        for (int j = 0; j < 8; ++j) {
          ahi[mt][j] = (short)(u[j] & 0xffffu);
          alo[mt][j] = (short)(u[j] >> 16);
        }
      }
      KSTEP(ahi, alo, wcur);
      __syncthreads();                      // cur read done; next staged+drained
    }
    if (lay == 0) {
      EPILOGUE_PACK(b2);                    // hbuf last read pre-barrier: safe
      __syncthreads();
    }
  }

  // ---- Layer 3 epilogue fused with Layer 4 (dot with W4) ----
  float p[2][4];
#pragma unroll
  for (int mt = 0; mt < 2; ++mt)
#pragma unroll
    for (int rr = 0; rr < 4; ++rr) p[mt][rr] = 0.0f;
#pragma unroll
  for (int nt = 0; nt < 4; ++nt) {
    float bv = b3[cb + nt * 16 + c];
    float wv = W4[cb + nt * 16 + c];
#pragma unroll
    for (int mt = 0; mt < 2; ++mt)
#pragma unroll
      for (int rr = 0; rr < 4; ++rr)
        p[mt][rr] += tanh_fast(acc[mt][nt][rr] + bv) * wv;
  }
  // reduce across the 16 column-lanes (xor 1,2,4,8 stays in each 16-group)
#pragma unroll
  for (int off = 1; off < 16; off <<= 1)
#pragma unroll
    for (int mt = 0; mt < 2; ++mt)
#pragma unroll
      for (int rr = 0; rr < 4; ++rr)
        p[mt][rr] += __shfl_xor(p[mt][rr], off, 64);
  // cross-wave (wc) reduction via LDS (reuse hbuf; last read was barriered;
  // per-wave slots disjoint: wc*64 + wr*32 + ...)
  float* red = (float*)hbuf;                // [4 wc][64 rows]
  if (c == 0) {
#pragma unroll
    for (int mt = 0; mt < 2; ++mt)
#pragma unroll
      for (int rr = 0; rr < 4; ++rr)
        red[wc * 64 + wr * 32 + mt * 16 + q * 4 + rr] = p[mt][rr];
  }
  __syncthreads();
  if (tid < 64) {
    int row = blk * 64 + tid;
    float s = red[tid] + red[64 + tid] + red[128 + tid] + red[192 + tid] + b4p[0];
    if (row < NN) out[row] = log_sigmoid_f(s);
  }
}

extern "C" void kernel_launch(void* const* d_in, const int* in_sizes, int n_in,
                              void* d_out, int out_size, void* d_ws, size_t ws_size,
                              hipStream_t stream) {
  // setup_inputs order: x(0), edge_index(1), edge_attr(2), W1(3), b1(4),
  //                     W2(5), b2(6), W3(7), b3(8), W4(9), b4(10)
  const float* ea = (const float*)d_in[2];
  const float* W1 = (const float*)d_in[3];
  const float* b1 = (const float*)d_in[4];
  const float* W2 = (const float*)d_in[5];
  const float* b2 = (const float*)d_in[6];
  const float* W3 = (const float*)d_in[7];
  const float* b3 = (const float*)d_in[8];
  const float* W4 = (const float*)d_in[9];
  const float* b4 = (const float*)d_in[10];

  // needs NCHUNK*32KB = 544KB of ws
  pack_weights<<<(NCHUNK * CHUNK_U32 + 255) / 256, 256, 0, stream>>>(
      W1, W2, W3, (uint16_t*)d_ws);
  mlp_fused<<<NBLK, 512, 0, stream>>>(ea, b1, b2, b3, W4, b4,
                                      (const uint32_t*)d_ws, (float*)d_out);
}

// Round 4
// 764.127 us; speedup vs baseline: 1.1882x; 1.1882x over previous
//
#include <hip/hip_runtime.h>
#include <stdint.h>

// Problem constants (from reference)
#define NN 500000          // nodes
#define HH 256             // hidden
#define NBLK ((NN + 63) / 64)   // 7813 blocks x 64 nodes
#define NCH 17             // weight chunks: W1:1, W2:8, W3:8
// ws layout: u16[NCH][2 planes(hi,lo)][256 n][32 k']  = 17 x 32KB = 544KB.
// B-frag for (nt,kc): lane(q,c) reads plane + (cb+nt*16+c)*32 + q*8 (8 u16,
// 16B aligned); a wave's 64 lanes cover 16 rows x 64B contiguous = 1KB. All
// weights stay L2-resident (544KB << 4MB/XCD) -> NO LDS staging, NO k-loop
// barriers (Common-mistake #7: don't stage L2-fit data).

typedef short short8 __attribute__((ext_vector_type(8)));
typedef float floatx4 __attribute__((ext_vector_type(4)));

__device__ __forceinline__ unsigned short f2bf(float f) {
  union { float f; uint32_t u; } v; v.f = f;
  uint32_t r = v.u + 0x7fffu + ((v.u >> 16) & 1u);   // RNE
  return (unsigned short)(r >> 16);
}
__device__ __forceinline__ float bf2f(unsigned short h) {
  union { uint32_t u; float f; } v; v.u = ((uint32_t)h) << 16;
  return v.f;
}
__device__ __forceinline__ float tanh_fast(float x) {
  float xc = fminf(fmaxf(x, -9.0f), 9.0f);           // tanh(9) == 1 - 3e-8
  float e = __expf(2.0f * xc);
  return __fdividef(e - 1.0f, e + 1.0f);
}
__device__ __forceinline__ float log_sigmoid_f(float x) {
  return fminf(x, 0.0f) - log1pf(__expf(-fabsf(x)));
}

// ---------------------------------------------------------------------------
// Pre-kernel: W1/W2/W3 (fp32 [k][n]) -> hi/lo bf16 planes in ws (layout above).
// Linear layout (no swizzle needed: these are read via global/L2, not LDS).
// Runs every launch (d_ws is re-poisoned by the harness).
// ---------------------------------------------------------------------------
__global__ void __launch_bounds__(256)
pack_weights(const float* __restrict__ W1, const float* __restrict__ W2,
             const float* __restrict__ W3, uint16_t* __restrict__ ws16) {
  int t = blockIdx.x * 256 + threadIdx.x;
  if (t >= NCH * 8192) return;
  int ch = t >> 13;             // chunk
  int r = t & 8191;
  int n  = r & 255;             // fast index -> coalesced source reads
  int kp = r >> 8;              // 0..31
  float w;
  if (ch == 0)      w = W1[kp * HH + n];
  else if (ch <= 8) w = W2[((ch - 1) * 32 + kp) * HH + n];
  else              w = W3[((ch - 9) * 32 + kp) * HH + n];
  unsigned short hi = f2bf(w);
  unsigned short lo = f2bf(w - bf2f(hi));
  uint16_t* p = ws16 + (size_t)ch * 16384 + n * 32 + kp;
  p[0]    = hi;                 // plane 0
  p[8192] = lo;                 // plane 1
}

// One k-step (k=32) for all (mt,nt): 3-pass hi/lo split MFMA, B from GLOBAL.
// D = Ahi*Bhi + Alo*Bhi + Ahi*Blo (AloBlo term ~2^-18 rel: dropped).
#define KSTEP_G(AHI, ALO, WG)                                                  \
  {                                                                            \
    const uint16_t* wg_ = (WG);                                                \
    _Pragma("unroll")                                                          \
    for (int nt = 0; nt < 4; ++nt) {                                           \
      short8 bhi = *(const short8*)(wg_ + woff + nt * 512);                    \
      short8 blo = *(const short8*)(wg_ + 8192 + woff + nt * 512);             \
      _Pragma("unroll")                                                        \
      for (int mt = 0; mt < 2; ++mt) {                                         \
        acc[mt][nt] = __builtin_amdgcn_mfma_f32_16x16x32_bf16(AHI[mt], bhi, acc[mt][nt], 0, 0, 0); \
        acc[mt][nt] = __builtin_amdgcn_mfma_f32_16x16x32_bf16(ALO[mt], bhi, acc[mt][nt], 0, 0, 0); \
        acc[mt][nt] = __builtin_amdgcn_mfma_f32_16x16x32_bf16(AHI[mt], blo, acc[mt][nt], 0, 0, 0); \
      }                                                                        \
    }                                                                          \
  }

#define ZEROACC()                                                              \
  {                                                                            \
    _Pragma("unroll") for (int mt = 0; mt < 2; ++mt)                           \
        _Pragma("unroll") for (int nt = 0; nt < 4; ++nt)                       \
            acc[mt][nt] = (floatx4){0.f, 0.f, 0.f, 0.f};                       \
  }

// bias + tanh + pack(hi|lo u32) + granule-XOR-swizzled store into hbuf.
// C/D layout (m89): col = lane&15 (c), row = q*4+rr. Verified: 0 bank confl.
#define EPILOGUE_PACK(BIAS)                                                    \
  {                                                                            \
    _Pragma("unroll")                                                          \
    for (int nt = 0; nt < 4; ++nt) {                                           \
      float bv = (BIAS)[cb + nt * 16 + c];                                     \
      _Pragma("unroll")                                                        \
      for (int mt = 0; mt < 2; ++mt) {                                         \
        _Pragma("unroll")                                                      \
        for (int rr = 0; rr < 4; ++rr) {                                       \
          float tv = tanh_fast(acc[mt][nt][rr] + bv);                          \
          unsigned short h_ = f2bf(tv);                                        \
          unsigned short l_ = f2bf(tv - bf2f(h_));                             \
          int row = wr * 32 + mt * 16 + q * 4 + rr;                            \
          int k = cb + nt * 16 + c;                                            \
          hbuf[row * 256 + ((((k >> 2) ^ (row & 15)) << 2) | (k & 3))] =       \
              (uint32_t)h_ | ((uint32_t)l_ << 16);                             \
        }                                                                      \
      }                                                                        \
    }                                                                          \
  }

// ---------------------------------------------------------------------------
// Fused 4-layer MLP. Block = 512 thr (8 waves, 2m x 4n), 64 nodes/block.
// Per wave: 32 rows x 64 cols, mfma_f32_16x16x32_bf16, hi/lo 3-pass.
// LDS: hbuf 64KB ONLY (packed h, swizzled). Weights read straight from L2.
// 64KB LDS + <=128 VGPR -> 2 blocks/CU, 4 waves/SIMD (__launch_bounds__(512,4)).
// Barriers: 5 per block total (layer transitions only; none in k-loops).
// ---------------------------------------------------------------------------
__global__ void __launch_bounds__(512, 4)
mlp_fused(const float* __restrict__ ea, const float* __restrict__ b1,
          const float* __restrict__ b2, const float* __restrict__ b3,
          const float* __restrict__ W4, const float* __restrict__ b4p,
          const uint16_t* __restrict__ wsw, float* __restrict__ out) {
  __shared__ uint32_t hbuf[16384];          // 64 KB: [64 rows][256 k] u32

  const int tid = threadIdx.x;
  const int wave = tid >> 6;
  const int lane = tid & 63;
  const int q = lane >> 4;                  // k-group / D-row-group
  const int c = lane & 15;                  // A-row / B-col / D-col lane
  const int wr = wave >> 2;                 // 0..1  (m)
  const int wc = wave & 3;                  // 0..3  (n)
  const int cb = wc * 64;
  const int blk = blockIdx.x;
  const int woff = (cb + c) * 32 + q * 8;   // u16 offset in a weight plane, nt=0

  floatx4 acc[2][4];

  // ---- load + hi/lo-split g fragments (A for layer 1: m=c, k=q*8+j) ----
  short8 g_hi[2], g_lo[2];
#pragma unroll
  for (int mt = 0; mt < 2; ++mt) {
    int row = blk * 64 + wr * 32 + mt * 16 + c;
    if (row >= NN) row = NN - 1;            // clamp (tail rows' outputs unused)
    const float* gp = ea + (size_t)row * 32 + q * 8;
    floatx4 v0 = *(const floatx4*)gp;
    floatx4 v1 = *(const floatx4*)(gp + 4);
    float g8[8] = {v0[0], v0[1], v0[2], v0[3], v1[0], v1[1], v1[2], v1[3]};
#pragma unroll
    for (int j = 0; j < 8; ++j) {
      unsigned short h_ = f2bf(g8[j]);
      g_hi[mt][j] = (short)h_;
      g_lo[mt][j] = (short)f2bf(g8[j] - bf2f(h_));
    }
  }

  // ---- Layer 1 (K=32: one k-step, chunk 0) ----
  ZEROACC();
  KSTEP_G(g_hi, g_lo, wsw);
  EPILOGUE_PACK(b1);
  __syncthreads();                          // h1 visible to all waves

  // ---- Layers 2 and 3: 8 k-steps each, weights from L2, no inner barriers --
#pragma unroll 1
  for (int lay = 0; lay < 2; ++lay) {
    ZEROACC();
#pragma unroll
    for (int kc = 0; kc < 8; ++kc) {
      const uint16_t* wg = wsw + (size_t)(1 + lay * 8 + kc) * 16384;
      // A fragments from packed h: k = kc*32 + q*8 + {0..7} of row (m=c)
      // -> u32 granules g0 = kc*8+q*2 and g0+1, positions XORed by row&15.
      short8 ahi[2], alo[2];
#pragma unroll
      for (int mt = 0; mt < 2; ++mt) {
        const int row = wr * 32 + mt * 16 + c;
        const uint32_t* hb = hbuf + row * 256;
        const int g0 = kc * 8 + q * 2;
        uint4 p0 = *(const uint4*)(hb + (((g0) ^ (row & 15)) << 2));
        uint4 p1 = *(const uint4*)(hb + (((g0 + 1) ^ (row & 15)) << 2));
        uint32_t u[8] = {p0.x, p0.y, p0.z, p0.w, p1.x, p1.y, p1.z, p1.w};
#pragma unroll
        for (int j = 0; j < 8; ++j) {
          ahi[mt][j] = (short)(u[j] & 0xffffu);
          alo[mt][j] = (short)(u[j] >> 16);
        }
      }
      KSTEP_G(ahi, alo, wg);
    }
    if (lay == 0) {
      __syncthreads();                      // all waves done READING h1
      EPILOGUE_PACK(b2);                    // overwrite hbuf with h2
      __syncthreads();                      // h2 visible
    }
  }

  // ---- Layer 3 epilogue fused with Layer 4 (dot with W4) ----
  float p[2][4];
#pragma unroll
  for (int mt = 0; mt < 2; ++mt)
#pragma unroll
    for (int rr = 0; rr < 4; ++rr) p[mt][rr] = 0.0f;
#pragma unroll
  for (int nt = 0; nt < 4; ++nt) {
    float bv = b3[cb + nt * 16 + c];
    float wv = W4[cb + nt * 16 + c];
#pragma unroll
    for (int mt = 0; mt < 2; ++mt)
#pragma unroll
      for (int rr = 0; rr < 4; ++rr)
        p[mt][rr] += tanh_fast(acc[mt][nt][rr] + bv) * wv;
  }
  // reduce across the 16 column-lanes (xor 1,2,4,8 stays in each 16-group)
#pragma unroll
  for (int off = 1; off < 16; off <<= 1)
#pragma unroll
    for (int mt = 0; mt < 2; ++mt)
#pragma unroll
      for (int rr = 0; rr < 4; ++rr)
        p[mt][rr] += __shfl_xor(p[mt][rr], off, 64);
  __syncthreads();                          // all waves done READING h2
  // cross-wave (wc) reduction via LDS (reuse hbuf; per-wave slots disjoint)
  float* red = (float*)hbuf;                // [4 wc][64 rows]
  if (c == 0) {
#pragma unroll
    for (int mt = 0; mt < 2; ++mt)
#pragma unroll
      for (int rr = 0; rr < 4; ++rr)
        red[wc * 64 + wr * 32 + mt * 16 + q * 4 + rr] = p[mt][rr];
  }
  __syncthreads();
  if (tid < 64) {
    int row = blk * 64 + tid;
    float s = red[tid] + red[64 + tid] + red[128 + tid] + red[192 + tid] + b4p[0];
    if (row < NN) out[row] = log_sigmoid_f(s);
  }
}

extern "C" void kernel_launch(void* const* d_in, const int* in_sizes, int n_in,
                              void* d_out, int out_size, void* d_ws, size_t ws_size,
                              hipStream_t stream) {
  // setup_inputs order: x(0), edge_index(1), edge_attr(2), W1(3), b1(4),
  //                     W2(5), b2(6), W3(7), b3(8), W4(9), b4(10)
  const float* ea = (const float*)d_in[2];
  const float* W1 = (const float*)d_in[3];
  const float* b1 = (const float*)d_in[4];
  const float* W2 = (const float*)d_in[5];
  const float* b2 = (const float*)d_in[6];
  const float* W3 = (const float*)d_in[7];
  const float* b3 = (const float*)d_in[8];
  const float* W4 = (const float*)d_in[9];
  const float* b4 = (const float*)d_in[10];

  // needs NCH*32KB = 544KB of ws
  pack_weights<<<(NCH * 8192 + 255) / 256, 256, 0, stream>>>(
      W1, W2, W3, (uint16_t*)d_ws);
  mlp_fused<<<NBLK, 512, 0, stream>>>(ea, b1, b2, b3, W4, b4,
                                      (const uint16_t*)d_ws, (float*)d_out);
}